// Round 9
// baseline (742.514 us; speedup 1.0000x reference)
//
#include <hip/hip_runtime.h>
#include <stdint.h>

#define RH 224
#define RW 224

// Zero-workspace scheme: d_out itself holds the per-pixel winner order (u32)
// during pass 1, then pass 2 replaces it in-place with the winner's depth.
//
// FP policy (FROZEN — bit-exact vs ref=np as of round 8, absmax 0.0):
// numpy f32 einsum scalar tail: FORWARD accumulation, separate mul/add
// rounds, no FMA; all later elementwise ops separately rounded.
// `#pragma clang fp contract(off)` everywhere FP happens.
//
// Perf (round 9): pass 1 was scattered-device-atomic bound (8M atomicMax ->
// 238 MB of memory-side sector RMWs, 8.6 atomics/cy device-wide ceiling).
// Fix: (a) reverse block->point mapping so highest orders dispatch first,
// (b) guard each atomic with a plain load and skip when order1 <= current.
// Guard reads can only be stale-LOW (L2 caches past committed values, values
// are monotone increasing) -> worst case a redundant atomic, never a miss.

#pragma clang fp contract(off)

__device__ __forceinline__ float dot3_fwd_nofma(float v0, float v1, float v2,
                                                const float* __restrict__ R,
                                                float t) {
#pragma clang fp contract(off)
    const float p0 = v0 * R[0];
    const float p1 = v1 * R[1];
    const float p2 = v2 * R[2];
    float acc = p0 + p1;
    acc = acc + p2;
    acc = acc + t;
    return acc;
}

// Pass 1: per-point projection; guarded atomicMax of (order+1) into d_out.
__global__ void proj_kernel(const float* __restrict__ vertices,
                            const float* __restrict__ rotation,
                            const float* __restrict__ translation,
                            const float* __restrict__ Kmat,
                            unsigned int* __restrict__ win,  // = d_out as u32
                            int N) {
#pragma clang fp contract(off)
    const int b = blockIdx.y;
    // Reverse block mapping: earliest-dispatched blocks own the HIGHEST point
    // indices (highest order wins), so the win buffer fills with near-final
    // values immediately and later blocks' guarded atomics mostly skip.
    const int rb = (int)gridDim.x - 1 - (int)blockIdx.x;
    const int n = rb * (int)blockDim.x + (int)threadIdx.x;
    if (n >= N) return;

    // Per-batch params: b is block-uniform -> scalar loads.
    const float* R = rotation + b * 9;
    const float* t = translation + b * 3;
    const float* k = Kmat + b * 9;
    const float fx = k[0], cx = k[2], fy = k[4], cy = k[5];

    const float* v = vertices + ((size_t)b * (size_t)N + (size_t)n) * 3;
    const float v0 = v[0], v1 = v[1], v2 = v[2];

    const float x = dot3_fwd_nofma(v0, v1, v2, R + 0, t[0]);
    const float y = dot3_fwd_nofma(v0, v1, v2, R + 3, t[1]);
    const float z = dot3_fwd_nofma(v0, v1, v2, R + 6, t[2]);

    const float Z = z + 1e-8f;          // separate round
    const float qx = x / Z;             // correctly-rounded f32 div
    const float qy = y / Z;
    float u = fx * qx;                  // separate mul
    u = u + cx;                         // separate add (contract off -> no fma)
    float w = fy * qy;
    w = w + cy;

    // trunc toward zero; validity on the truncated float (matches numpy
    // trunc->astype(int32)->bounds, incl. -0.0 and huge/NaN cases).
    const float tu = truncf(u);
    const float tv = truncf(w);
    if (tu >= 0.0f && tu < (float)RW && tv >= 0.0f && tv < (float)RH) {
        const int ui = (int)tu;
        const int vi = (int)tv;
        const int pix = b * (RH * RW) + vi * RW + ui;
        const unsigned int order1 = (unsigned int)(b * N + n) + 1u;  // 0 == empty
        // Guarded atomic: plain load (XCD-L2 cached, possibly stale-low).
        const unsigned int cur = win[pix];
        if (order1 > cur) {
            atomicMax(&win[pix], order1);
        }
    }
}

// Pass 2: in-place decode winner order -> depth (recomputed with the identical
// FP sequence). Empty pixels (order 0) -> 0.0f.
__global__ void resolve_kernel(unsigned int* __restrict__ buf,  // = d_out
                               const float* __restrict__ vertices,
                               const float* __restrict__ rotation,
                               const float* __restrict__ translation,
                               int N, int P) {
#pragma clang fp contract(off)
    const int i = blockIdx.x * blockDim.x + threadIdx.x;
    if (i >= P) return;
    const unsigned int o1 = buf[i];
    float depth = 0.0f;
    if (o1 != 0u) {
        const unsigned int o = o1 - 1u;
        const int b = (int)(o / (unsigned int)N);
        const int n = (int)(o % (unsigned int)N);
        const float* v = vertices + ((size_t)b * (size_t)N + (size_t)n) * 3;
        const float* R = rotation + b * 9;
        depth = dot3_fwd_nofma(v[0], v[1], v[2], R + 6, translation[b * 3 + 2]);
    }
    buf[i] = __float_as_uint(depth);  // final f32 image, written as bits
}

extern "C" void kernel_launch(void* const* d_in, const int* in_sizes, int n_in,
                              void* d_out, int out_size, void* d_ws, size_t ws_size,
                              hipStream_t stream) {
    const float* vertices    = (const float*)d_in[0];
    const float* rotation    = (const float*)d_in[1];
    const float* translation = (const float*)d_in[2];
    const float* Kmat        = (const float*)d_in[3];

    const int B = in_sizes[1] / 9;              // rotation is B*3*3
    const int N = in_sizes[0] / (3 * B);        // vertices is B*N*3
    const int P = B * RH * RW;                  // == out_size

    unsigned int* win = (unsigned int*)d_out;

    // d_out must start at 0 every call (harness poisons once, never restores).
    hipMemsetAsync(win, 0, (size_t)P * sizeof(unsigned int), stream);

    dim3 block(256);
    dim3 grid((N + 255) / 256, B);
    proj_kernel<<<grid, block, 0, stream>>>(vertices, rotation, translation, Kmat, win, N);

    const int rblocks = (P + 255) / 256;
    resolve_kernel<<<rblocks, 256, 0, stream>>>(win, vertices, rotation, translation, N, P);
}

// Round 10
// 90.030 us; speedup vs baseline: 8.2474x; 8.2474x over previous
//
#include <hip/hip_runtime.h>
#include <stdint.h>

#define RH 224
#define RW 224
#define NSTRIPE 4                      // row-stripes per image
#define NCHUNK 4                       // point-chunks per batch
#define STRIPE_ROWS (RH / NSTRIPE)     // 56
#define STRIPE_PX (STRIPE_ROWS * RW)   // 12544 -> 49KB LDS (u32)
#define BLOCK_THREADS 1024

// FP policy (FROZEN — bit-exact vs ref=np since round 8, absmax 0.0):
// numpy f32 einsum scalar tail: FORWARD accumulation, separate mul/add
// rounds, no FMA; all later elementwise ops separately rounded.
// `#pragma clang fp contract(off)` everywhere FP happens.
//
// Perf history: r8 = 8M scattered device atomics, 389us (atomic-op bound,
// VALU 3.5%). r9 guard-load variant REGRESSED (739us: 8M dependent guard
// loads all missed to HBM). r10: LDS z-buffer stripes -> global atomics
// become per-stripe coalesced flushes; scattered-line RMWs drop ~20x.

#pragma clang fp contract(off)

__device__ __forceinline__ float dot3_fwd_nofma(float v0, float v1, float v2,
                                                float R0, float R1, float R2,
                                                float t) {
#pragma clang fp contract(off)
    const float p0 = v0 * R0;
    const float p1 = v1 * R1;
    const float p2 = v2 * R2;
    float acc = p0 + p1;
    acc = acc + p2;
    acc = acc + t;
    return acc;
}

// Pass 1: blocks = (batch b, stripe s, chunk c). Project chunk points; LDS
// atomicMax into the stripe z-buffer; coalesced global atomicMax flush.
__global__ __launch_bounds__(BLOCK_THREADS) void
proj_kernel(const float* __restrict__ vertices,
            const float* __restrict__ rotation,
            const float* __restrict__ translation,
            const float* __restrict__ Kmat,
            unsigned int* __restrict__ win,  // = d_out as u32
            int N) {
#pragma clang fp contract(off)
    __shared__ unsigned int sbuf[STRIPE_PX];

    const int blk = (int)blockIdx.x;
    const int s   = blk & (NSTRIPE - 1);            // stripe varies fastest:
    const int c   = (blk >> 2) & (NCHUNK - 1);      // stripes of one chunk
    const int b   = blk >> 4;                       // share vertex reads in L3

    for (int j = threadIdx.x; j < STRIPE_PX; j += BLOCK_THREADS) sbuf[j] = 0u;
    __syncthreads();

    // Per-batch params (block-uniform -> scalar regs).
    const float* R = rotation + b * 9;
    const float* t = translation + b * 3;
    const float* k = Kmat + b * 9;
    const float fx = k[0], cx = k[2], fy = k[4], cy = k[5];
    const float R00 = R[0], R01 = R[1], R02 = R[2];
    const float R10 = R[3], R11 = R[4], R12 = R[5];
    const float R20 = R[6], R21 = R[7], R22 = R[8];
    const float t0 = t[0], t1 = t[1], t2 = t[2];

    const int chunk  = (N + NCHUNK - 1) / NCHUNK;
    const int n_beg  = c * chunk;
    const int n_end  = min(N, n_beg + chunk);
    const int nquads = (n_end - n_beg + 3) >> 2;
    const float v_lo = (float)(s * STRIPE_ROWS);
    const float v_hi = (float)((s + 1) * STRIPE_ROWS);

    for (int q = threadIdx.x; q < nquads; q += BLOCK_THREADS) {
        const int n0 = n_beg + (q << 2);
        // 4 points = 48B = 3x float4, fully coalesced (n0 is a multiple of 4).
        const float4* vp = (const float4*)(vertices + ((size_t)b * N + n0) * 3);
        const float4 f0 = vp[0], f1 = vp[1], f2 = vp[2];
        const float px[4][3] = {{f0.x, f0.y, f0.z}, {f0.w, f1.x, f1.y},
                                {f1.z, f1.w, f2.x}, {f2.y, f2.z, f2.w}};
#pragma unroll
        for (int kk = 0; kk < 4; ++kk) {
            const int n = n0 + kk;
            if (n >= n_end) break;
            const float v0 = px[kk][0], v1 = px[kk][1], v2 = px[kk][2];

            // FROZEN FP ORDER. v-row first: off-stripe points skip x/u math.
            const float y = dot3_fwd_nofma(v0, v1, v2, R10, R11, R12, t1);
            const float z = dot3_fwd_nofma(v0, v1, v2, R20, R21, R22, t2);
            const float Z = z + 1e-8f;          // separate round
            const float qy = y / Z;             // correctly-rounded div
            float w = fy * qy;                  // separate mul
            w = w + cy;                         // separate add
            const float tv = truncf(w);
            if (!(tv >= v_lo && tv < v_hi)) continue;   // NaN -> skip (== ref)

            const float x = dot3_fwd_nofma(v0, v1, v2, R00, R01, R02, t0);
            const float qx = x / Z;
            float u = fx * qx;
            u = u + cx;
            const float tu = truncf(u);
            if (!(tu >= 0.0f && tu < (float)RW)) continue;

            const int ui = (int)tu;
            const int vi = (int)tv;
            const int slot = (vi - s * STRIPE_ROWS) * RW + ui;
            const unsigned int order1 = (unsigned int)(b * N + n) + 1u;
            atomicMax(&sbuf[slot], order1);     // LDS atomic: cheap
        }
    }
    __syncthreads();

    // Coalesced flush: NCHUNK blocks share each stripe -> global atomicMax.
    unsigned int* g = win + b * (RH * RW) + s * STRIPE_PX;
    for (int j = threadIdx.x; j < STRIPE_PX; j += BLOCK_THREADS) {
        const unsigned int val = sbuf[j];
        if (val) atomicMax(&g[j], val);
    }
}

// Pass 2: in-place decode winner order -> depth (identical FP sequence).
__global__ void resolve_kernel(unsigned int* __restrict__ buf,  // = d_out
                               const float* __restrict__ vertices,
                               const float* __restrict__ rotation,
                               const float* __restrict__ translation,
                               int N, int P) {
#pragma clang fp contract(off)
    const int i = blockIdx.x * blockDim.x + threadIdx.x;
    if (i >= P) return;
    const unsigned int o1 = buf[i];
    float depth = 0.0f;
    if (o1 != 0u) {
        const unsigned int o = o1 - 1u;
        const int b = (int)(o / (unsigned int)N);
        const int n = (int)(o % (unsigned int)N);
        const float* v = vertices + ((size_t)b * (size_t)N + (size_t)n) * 3;
        const float* R = rotation + b * 9;
        depth = dot3_fwd_nofma(v[0], v[1], v[2], R[6], R[7], R[8],
                               translation[b * 3 + 2]);
    }
    buf[i] = __float_as_uint(depth);  // final f32 image, written as bits
}

extern "C" void kernel_launch(void* const* d_in, const int* in_sizes, int n_in,
                              void* d_out, int out_size, void* d_ws, size_t ws_size,
                              hipStream_t stream) {
    const float* vertices    = (const float*)d_in[0];
    const float* rotation    = (const float*)d_in[1];
    const float* translation = (const float*)d_in[2];
    const float* Kmat        = (const float*)d_in[3];

    const int B = in_sizes[1] / 9;              // rotation is B*3*3
    const int N = in_sizes[0] / (3 * B);        // vertices is B*N*3
    const int P = B * RH * RW;                  // == out_size

    unsigned int* win = (unsigned int*)d_out;

    // d_out must start at 0 every call (harness poisons once, never restores).
    hipMemsetAsync(win, 0, (size_t)P * sizeof(unsigned int), stream);

    dim3 grid(B * NSTRIPE * NCHUNK);
    proj_kernel<<<grid, BLOCK_THREADS, 0, stream>>>(vertices, rotation,
                                                    translation, Kmat, win, N);

    const int rblocks = (P + 255) / 256;
    resolve_kernel<<<rblocks, 256, 0, stream>>>(win, vertices, rotation,
                                                translation, N, P);
}

// Round 11
// 69.652 us; speedup vs baseline: 10.6603x; 1.2926x over previous
//
#include <hip/hip_runtime.h>
#include <stdint.h>

#define RH 224
#define RW 224
#define NSTRIPE 2                      // row-stripes per image
#define NCHUNK 8                       // point-chunks per batch
#define STRIPE_ROWS (RH / NSTRIPE)     // 112
#define STRIPE_PX (STRIPE_ROWS * RW)   // 25088 -> 100352 B LDS (u32, dynamic)
#define BLOCK_THREADS 1024

// FP policy (FROZEN — bit-exact vs ref=np since round 8, absmax 0.0):
// numpy f32 einsum scalar tail: FORWARD accumulation, separate mul/add
// rounds, no FMA; all later elementwise ops separately rounded.
// `#pragma clang fp contract(off)` everywhere FP happens.
//
// Perf history:
//  r8  389us: 8M scattered device atomics (atomic-op bound, VALU 3.5%)
//  r9  739us: guard-load REGRESSED (8M dependent HBM guard reads)
//  r10  81us: LDS stripe z-buffer, NSTRIPE=4 (VALU-bound: 65% busy,
//             4x redundant v-row projection incl. exact f32 div)
//  r11: NSTRIPE=2 via 100KB dynamic LDS (gfx950 has 160KB/CU; >64KB needs
//       dynamic extern __shared__), NCHUNK=8. Redundancy 4x->2x.

#pragma clang fp contract(off)

__device__ __forceinline__ float dot3_fwd_nofma(float v0, float v1, float v2,
                                                float R0, float R1, float R2,
                                                float t) {
#pragma clang fp contract(off)
    const float p0 = v0 * R0;
    const float p1 = v1 * R1;
    const float p2 = v2 * R2;
    float acc = p0 + p1;
    acc = acc + p2;
    acc = acc + t;
    return acc;
}

// Pass 1: blocks = (batch b, stripe s, chunk c). Project chunk points; LDS
// atomicMax into the stripe z-buffer; coalesced global atomicMax flush.
__global__ __launch_bounds__(BLOCK_THREADS) void
proj_kernel(const float* __restrict__ vertices,
            const float* __restrict__ rotation,
            const float* __restrict__ translation,
            const float* __restrict__ Kmat,
            unsigned int* __restrict__ win,  // = d_out as u32
            int N) {
#pragma clang fp contract(off)
    extern __shared__ unsigned int sbuf[];   // STRIPE_PX u32 = 100352 B

    const int blk = (int)blockIdx.x;
    const int s   = blk & (NSTRIPE - 1);             // stripe fastest
    const int c   = (blk >> 1) & (NCHUNK - 1);       // then chunk
    const int b   = blk >> 4;                        // then batch

    for (int j = threadIdx.x; j < STRIPE_PX; j += BLOCK_THREADS) sbuf[j] = 0u;
    __syncthreads();

    // Per-batch params (block-uniform -> scalar regs).
    const float* R = rotation + b * 9;
    const float* t = translation + b * 3;
    const float* k = Kmat + b * 9;
    const float fx = k[0], cx = k[2], fy = k[4], cy = k[5];
    const float R00 = R[0], R01 = R[1], R02 = R[2];
    const float R10 = R[3], R11 = R[4], R12 = R[5];
    const float R20 = R[6], R21 = R[7], R22 = R[8];
    const float t0 = t[0], t1 = t[1], t2 = t[2];

    const int chunk  = (N + NCHUNK - 1) / NCHUNK;
    const int n_beg  = c * chunk;
    const int n_end  = min(N, n_beg + chunk);
    const int nquads = (n_end - n_beg + 3) >> 2;
    const float v_lo = (float)(s * STRIPE_ROWS);
    const float v_hi = (float)((s + 1) * STRIPE_ROWS);

    for (int q = threadIdx.x; q < nquads; q += BLOCK_THREADS) {
        const int n0 = n_beg + (q << 2);
        // 4 points = 48B = 3x float4, fully coalesced (n0 multiple of 4).
        const float4* vp = (const float4*)(vertices + ((size_t)b * N + n0) * 3);
        const float4 f0 = vp[0], f1 = vp[1], f2 = vp[2];
        const float px[4][3] = {{f0.x, f0.y, f0.z}, {f0.w, f1.x, f1.y},
                                {f1.z, f1.w, f2.x}, {f2.y, f2.z, f2.w}};
#pragma unroll
        for (int kk = 0; kk < 4; ++kk) {
            const int n = n0 + kk;
            if (n >= n_end) break;
            const float v0 = px[kk][0], v1 = px[kk][1], v2 = px[kk][2];

            // FROZEN FP ORDER. v-row first: off-stripe points skip x/u math.
            const float y = dot3_fwd_nofma(v0, v1, v2, R10, R11, R12, t1);
            const float z = dot3_fwd_nofma(v0, v1, v2, R20, R21, R22, t2);
            const float Z = z + 1e-8f;          // separate round
            const float qy = y / Z;             // correctly-rounded div
            float w = fy * qy;                  // separate mul
            w = w + cy;                         // separate add
            const float tv = truncf(w);
            if (!(tv >= v_lo && tv < v_hi)) continue;   // NaN -> skip (== ref)

            const float x = dot3_fwd_nofma(v0, v1, v2, R00, R01, R02, t0);
            const float qx = x / Z;
            float u = fx * qx;
            u = u + cx;
            const float tu = truncf(u);
            if (!(tu >= 0.0f && tu < (float)RW)) continue;

            const int ui = (int)tu;
            const int vi = (int)tv;
            const int slot = (vi - s * STRIPE_ROWS) * RW + ui;
            const unsigned int order1 = (unsigned int)(b * N + n) + 1u;
            atomicMax(&sbuf[slot], order1);     // LDS atomic: cheap
        }
    }
    __syncthreads();

    // Coalesced flush: NCHUNK blocks share each stripe -> global atomicMax.
    unsigned int* g = win + b * (RH * RW) + s * STRIPE_PX;
    for (int j = threadIdx.x; j < STRIPE_PX; j += BLOCK_THREADS) {
        const unsigned int val = sbuf[j];
        if (val) atomicMax(&g[j], val);
    }
}

// Pass 2: in-place decode winner order -> depth (identical FP sequence).
__global__ void resolve_kernel(unsigned int* __restrict__ buf,  // = d_out
                               const float* __restrict__ vertices,
                               const float* __restrict__ rotation,
                               const float* __restrict__ translation,
                               int N, int P) {
#pragma clang fp contract(off)
    const int i = blockIdx.x * blockDim.x + threadIdx.x;
    if (i >= P) return;
    const unsigned int o1 = buf[i];
    float depth = 0.0f;
    if (o1 != 0u) {
        const unsigned int o = o1 - 1u;
        const int b = (int)(o / (unsigned int)N);
        const int n = (int)(o % (unsigned int)N);
        const float* v = vertices + ((size_t)b * (size_t)N + (size_t)n) * 3;
        const float* R = rotation + b * 9;
        depth = dot3_fwd_nofma(v[0], v[1], v[2], R[6], R[7], R[8],
                               translation[b * 3 + 2]);
    }
    buf[i] = __float_as_uint(depth);  // final f32 image, written as bits
}

extern "C" void kernel_launch(void* const* d_in, const int* in_sizes, int n_in,
                              void* d_out, int out_size, void* d_ws, size_t ws_size,
                              hipStream_t stream) {
    const float* vertices    = (const float*)d_in[0];
    const float* rotation    = (const float*)d_in[1];
    const float* translation = (const float*)d_in[2];
    const float* Kmat        = (const float*)d_in[3];

    const int B = in_sizes[1] / 9;              // rotation is B*3*3
    const int N = in_sizes[0] / (3 * B);        // vertices is B*N*3
    const int P = B * RH * RW;                  // == out_size

    unsigned int* win = (unsigned int*)d_out;

    // d_out must start at 0 every call (harness poisons once, never restores).
    hipMemsetAsync(win, 0, (size_t)P * sizeof(unsigned int), stream);

    dim3 grid(B * NSTRIPE * NCHUNK);            // 256 blocks = 1/CU
    proj_kernel<<<grid, BLOCK_THREADS, STRIPE_PX * sizeof(unsigned int), stream>>>(
        vertices, rotation, translation, Kmat, win, N);

    const int rblocks = (P + 255) / 256;
    resolve_kernel<<<rblocks, 256, 0, stream>>>(win, vertices, rotation,
                                                translation, N, P);
}